// Round 10
// baseline (455.418 us; speedup 1.0000x reference)
//
#include <hip/hip_runtime.h>

#define BB  8
#define NN1 1024
#define NN2 256
#define DD  16
#define EE  16
#define NCOL (NN2 * DD)   // 4096

using bf16x8  = __attribute__((ext_vector_type(8))) short;
using f32x4   = __attribute__((ext_vector_type(4))) float;
using ushort8 = __attribute__((ext_vector_type(8))) unsigned short;

__device__ __forceinline__ ushort f2bf(float x) {
  unsigned u = __float_as_uint(x);
  unsigned r = (u + 0x7FFFu + ((u >> 16) & 1u)) >> 16;
  return (ushort)r;
}
__device__ __forceinline__ float bf2f(ushort u) {
  return __uint_as_float((unsigned)u << 16);
}
__device__ __forceinline__ unsigned pkbf(float a, float b) {
  return (unsigned)f2bf(a) | ((unsigned)f2bf(b) << 16);
}

#define GLDS16(g, l)                                                       \
  __builtin_amdgcn_global_load_lds(                                        \
      (const __attribute__((address_space(1))) void*)(g),                  \
      (__attribute__((address_space(3))) void*)(l), 16, 0, 0)

// ---------------------------------------------------------------------------
// k_prep: transpose + fp32->bf16 + swizzle.
//  - 16B-chunk XOR within each 64B block: chunk g <- g ^ ((row>>1)&3)
//  - if ps: additionally swap the two 64B blocks of each 128B pair on odd rows
//    (keeps ds_read_b128 2-way at the 8-phase kernel's 128B LDS row stride)
// src fp32 [kd(k)][nr], dst bf16 [nr][kd].
// ---------------------------------------------------------------------------
__global__ __launch_bounds__(256)
void k_prep(const float* __restrict__ src, ushort* __restrict__ dst,
            int nr, int kd, size_t srcBatch, size_t dstBatch, int ps) {
  __shared__ float tile[64][65];
  const int t = threadIdx.x;
  const int r0 = blockIdx.x * 64;
  const int k0 = blockIdx.y * 64;
  const float* s = src + (size_t)blockIdx.z * srcBatch;
  ushort* d = dst + (size_t)blockIdx.z * dstBatch;

#pragma unroll
  for (int it = 0; it < 4; ++it) {
    const int kr = it * 16 + (t >> 4);
    const int rc = (t & 15) * 4;
    float4 v = *reinterpret_cast<const float4*>(&s[(size_t)(k0 + kr) * nr + r0 + rc]);
    tile[kr][rc] = v.x; tile[kr][rc + 1] = v.y;
    tile[kr][rc + 2] = v.z; tile[kr][rc + 3] = v.w;
  }
  __syncthreads();

#pragma unroll
  for (int pass = 0; pass < 2; ++pass) {
    const int task = t + pass * 256;
    const int pr = task >> 3;
    const int gl = task & 7;
    const int r = r0 + pr;
    const int f = (r >> 1) & 3;
    const int lb = (gl >> 2) ^ (ps & r);            // 64B-block pair swap (odd rows)
    const int klb = (lb & 1) * 32 + ((gl & 3) ^ f) * 8;
    unsigned w[4];
#pragma unroll
    for (int e2 = 0; e2 < 4; ++e2)
      w[e2] = pkbf(tile[klb + e2 * 2][pr], tile[klb + e2 * 2 + 1][pr]);
    *reinterpret_cast<uint4*>(&d[(size_t)r * kd + k0 + gl * 8]) =
        *reinterpret_cast<const uint4*>(w);
  }
}

// ---------------------------------------------------------------------------
// k_mode0_mfma: y[b][p][c] = sum_k adj0[k][p] * X[b][k][c] -> bf16
// 256x256 tile, BK=64, 8 waves (2p x 4c), per-wave 128x64 output.
// 8-phase schedule (T3+T4+T5): each phase = {issue 1 half-tile stage (2 GLDS16),
// vmcnt(6), barrier, 12 ds_read_b128, 16 MFMA in setprio(1)}. Uniform vmcnt(6)
// verified by per-wave enumeration; last iter drains 4/2/0.
// ---------------------------------------------------------------------------
__global__ __launch_bounds__(512, 2)
void k_mode0_mfma(const ushort* __restrict__ At, const ushort* __restrict__ Xt,
                  ushort* __restrict__ Y) {
  __shared__ ushort As[2][16384];   // [buf][256 rows x 64 k]
  __shared__ ushort Bs[2][16384];

  const int t = threadIdx.x;
  const int lane = t & 63;
  const int wid = t >> 6;           // 0..7
  const int wm = wid >> 2;          // p half
  const int wn = wid & 3;           // c quarter

  // XCD-chunked bijective swizzle (nwg % 8 == 0 always: nwg = nb*64)
  const int nwg = (int)gridDim.x;
  const int wg  = (int)blockIdx.x;
  const int orig = (wg & 7) * (nwg >> 3) + (wg >> 3);
  const int b  = orig >> 6;
  const int rem = orig & 63;
  const int c0 = (rem >> 2) << 8;   // 16 c-tiles
  const int p0 = (rem & 3) << 8;    // 4 p-tiles

  const ushort* Bb = Xt + (size_t)b * (NCOL * 1024);

  f32x4 acc[8][4];
#pragma unroll
  for (int i = 0; i < 8; ++i)
#pragma unroll
    for (int j = 0; j < 4; ++j) acc[i][j] = (f32x4)0.f;

  const int lm = lane & 15, g = lane >> 4;
  const int kswz = (lm & 1) << 5;   // 64B-block swap on odd rows (ushort units)

  int aoff[8], boff[4];
#pragma unroll
  for (int f = 0; f < 8; ++f) {
    const int ra = wm * 128 + f * 16 + lm;
    aoff[f] = ra * 64 + ((g ^ ((ra >> 1) & 3)) << 3);
  }
#pragma unroll
  for (int f = 0; f < 4; ++f) {
    const int rb = wn * 64 + f * 16 + lm;
    boff[f] = rb * 64 + ((g ^ ((rb >> 1) & 3)) << 3);
  }

  // staging: half-tile = 2 GLDS16 (is=0,1); rows covered derived per wave
#define STG_A(buf, kt, hA) do {                                            \
    { const int r0_ = (hA) * 64 + wid * 8;                                 \
      GLDS16(At + (size_t)(p0 + r0_ + (lane >> 3)) * 1024 + (kt) * 64 +    \
                 (lane & 7) * 8, &As[buf][r0_ * 64]); }                    \
    { const int r0_ = (hA) * 64 + 128 + wid * 8;                           \
      GLDS16(At + (size_t)(p0 + r0_ + (lane >> 3)) * 1024 + (kt) * 64 +    \
                 (lane & 7) * 8, &As[buf][r0_ * 64]); }                    \
  } while (0)

#define STG_B(buf, kt, hB) do {                                            \
    { const int r0_ = (wid >> 2) * 64 + (hB) * 32 + (wid & 3) * 8;         \
      GLDS16(Bb + (size_t)(c0 + r0_ + (lane >> 3)) * 1024 + (kt) * 64 +    \
                 (lane & 7) * 8, &Bs[buf][r0_ * 64]); }                    \
    { const int r0_ = (2 + (wid >> 2)) * 64 + (hB) * 32 + (wid & 3) * 8;   \
      GLDS16(Bb + (size_t)(c0 + r0_ + (lane >> 3)) * 1024 + (kt) * 64 +    \
                 (lane & 7) * 8, &Bs[buf][r0_ * 64]); }                    \
  } while (0)

#define VM6 asm volatile("s_waitcnt vmcnt(6)" ::: "memory")
#define VM4 asm volatile("s_waitcnt vmcnt(4)" ::: "memory")
#define VM2 asm volatile("s_waitcnt vmcnt(2)" ::: "memory")
#define VM0 asm volatile("s_waitcnt vmcnt(0)" ::: "memory")
#define NOWAIT ((void)0)
#define NOSTG  ((void)0)

#define PHASE(buf, qi, qj, STGSTMT, WAITSTMT) do {                         \
    STGSTMT;                                                               \
    WAITSTMT;                                                              \
    __builtin_amdgcn_s_barrier();                                          \
    __builtin_amdgcn_sched_barrier(0);                                     \
    bf16x8 a_[4][2], b_[2][2];                                             \
    _Pragma("unroll")                                                      \
    for (int i_ = 0; i_ < 4; ++i_)                                         \
      _Pragma("unroll")                                                    \
      for (int ks_ = 0; ks_ < 2; ++ks_)                                    \
        a_[i_][ks_] = *reinterpret_cast<const bf16x8*>(                    \
            &As[buf][aoff[(qi) * 4 + i_] + ((ks_ << 5) ^ kswz)]);          \
    _Pragma("unroll")                                                      \
    for (int j_ = 0; j_ < 2; ++j_)                                         \
      _Pragma("unroll")                                                    \
      for (int ks_ = 0; ks_ < 2; ++ks_)                                    \
        b_[j_][ks_] = *reinterpret_cast<const bf16x8*>(                    \
            &Bs[buf][boff[(qj) * 2 + j_] + ((ks_ << 5) ^ kswz)]);          \
    __builtin_amdgcn_s_setprio(1);                                         \
    _Pragma("unroll")                                                      \
    for (int ks_ = 0; ks_ < 2; ++ks_)                                      \
      _Pragma("unroll")                                                    \
      for (int i_ = 0; i_ < 4; ++i_)                                       \
        _Pragma("unroll")                                                  \
        for (int j_ = 0; j_ < 2; ++j_)                                     \
          acc[(qi) * 4 + i_][(qj) * 2 + j_] =                              \
              __builtin_amdgcn_mfma_f32_16x16x32_bf16(                     \
                  a_[i_][ks_], b_[j_][ks_],                                \
                  acc[(qi) * 4 + i_][(qj) * 2 + j_], 0, 0, 0);             \
    __builtin_amdgcn_s_setprio(0);                                         \
  } while (0)

  // prologue: tile 0 -> buf0, halves in order A0,B0,A1,B1 (8 loads)
  STG_A(0, 0, 0); STG_B(0, 0, 0); STG_A(0, 0, 1); STG_B(0, 0, 1);

  for (int it = 0; it < 8; ++it) {
    const int t1 = 2 * it + 1, t2 = 2 * it + 2;
    // phases 1-4: compute tile 2it (buf0); stage tile 2it+1 -> buf1
    PHASE(0, 0, 0, STG_A(1, t1, 0), VM6);
    PHASE(0, 1, 0, STG_B(1, t1, 0), VM6);
    PHASE(0, 0, 1, STG_A(1, t1, 1), VM6);
    PHASE(0, 1, 1, STG_B(1, t1, 1), VM6);
    __builtin_amdgcn_s_barrier();
    // phases 5-8: compute tile 2it+1 (buf1); stage tile 2it+2 -> buf0
    if (it < 7) {
      PHASE(1, 0, 0, STG_A(0, t2, 0), VM6);
      PHASE(1, 1, 0, STG_B(0, t2, 0), VM6);
      PHASE(1, 0, 1, STG_A(0, t2, 1), VM6);
      PHASE(1, 1, 1, STG_B(0, t2, 1), VM6);
    } else {
      PHASE(1, 0, 0, NOSTG, VM4);
      PHASE(1, 1, 0, NOSTG, VM2);
      PHASE(1, 0, 1, NOSTG, VM0);
      PHASE(1, 1, 1, NOSTG, NOWAIT);
    }
    __builtin_amdgcn_s_barrier();
  }
#undef PHASE
#undef STG_A
#undef STG_B

  ushort* Yb = Y + (size_t)b * ((size_t)NN1 * NCOL);
  const int orow = g * 4;
#pragma unroll
  for (int i = 0; i < 8; ++i)
#pragma unroll
    for (int j = 0; j < 4; ++j) {
      const int p = p0 + wm * 128 + i * 16 + orow;
      const int c = c0 + wn * 64 + j * 16 + lm;
      ushort* dst = Yb + (size_t)p * NCOL + c;
#pragma unroll
      for (int e = 0; e < 4; ++e) dst[(size_t)e * NCOL] = f2bf(acc[i][j][e]);
    }
}

// ---------------------------------------------------------------------------
// k_proj: per (b,p) slice, thread j:
//   r[j,e] = x@W + y0@W_s0 + sum(bias)  -> rb (bf16, [slice][j][e])
//   s[j,e] = x@W_s1 + y0@W_s01          -> st (bf16, swizzled, [slice*16+e][j])
// ---------------------------------------------------------------------------
__global__ __launch_bounds__(256)
void k_proj(const float* __restrict__ x, const ushort* __restrict__ y0,
            ushort* __restrict__ st, ushort* __restrict__ rb,
            const float* __restrict__ W,   const float* __restrict__ bW,
            const float* __restrict__ W0,  const float* __restrict__ b0,
            const float* __restrict__ W1,  const float* __restrict__ b1,
            const float* __restrict__ W01, const float* __restrict__ b01) {
  __shared__ float sW[4][DD][EE];
  __shared__ float sbias[EE];

  const int t = threadIdx.x;
  {
    const int m = t >> 6;
    const int r = t & 63;
    const float* Wp = (m == 0) ? W : (m == 1) ? W0 : (m == 2) ? W1 : W01;
    reinterpret_cast<float4*>(&sW[m][0][0])[r] =
        reinterpret_cast<const float4*>(Wp)[r];
  }
  if (t < EE) sbias[t] = bW[t] + b0[t] + b1[t] + b01[t];
  __syncthreads();

  const size_t base = (size_t)blockIdx.x * NCOL + (size_t)t * DD;

  float xr[DD], yr[DD];
#pragma unroll
  for (int v = 0; v < 4; ++v)
    *reinterpret_cast<float4*>(&xr[v * 4]) =
        *reinterpret_cast<const float4*>(&x[base + v * 4]);
  {
    ushort8 ya = *reinterpret_cast<const ushort8*>(&y0[base]);
    ushort8 yb = *reinterpret_cast<const ushort8*>(&y0[base + 8]);
#pragma unroll
    for (int k = 0; k < 8; ++k) { yr[k] = bf2f(ya[k]); yr[8 + k] = bf2f(yb[k]); }
  }

  float r[EE], s[EE];
#pragma unroll
  for (int e = 0; e < EE; ++e) { r[e] = sbias[e]; s[e] = 0.f; }

#pragma unroll
  for (int d = 0; d < DD; ++d) {
    const float xd = xr[d], yd = yr[d];
#pragma unroll
    for (int e = 0; e < EE; ++e) {
      r[e] = fmaf(xd, sW[0][d][e], r[e]);
      r[e] = fmaf(yd, sW[1][d][e], r[e]);
      s[e] = fmaf(xd, sW[2][d][e], s[e]);
      s[e] = fmaf(yd, sW[3][d][e], s[e]);
    }
  }

  {
    ushort rw[16];
#pragma unroll
    for (int e = 0; e < EE; ++e) rw[e] = f2bf(r[e]);
    *reinterpret_cast<uint4*>(&rb[base])     = *reinterpret_cast<const uint4*>(&rw[0]);
    *reinterpret_cast<uint4*>(&rb[base + 8]) = *reinterpret_cast<const uint4*>(&rw[8]);
  }

  const size_t stbase = (size_t)blockIdx.x * (EE * NN2);
#pragma unroll
  for (int e = 0; e < EE; ++e) {
    const int f = (e >> 1) & 3;
    const int off = (t >> 5) * 32 + ((((t >> 3) & 3) ^ f) << 3) + (t & 7);
    st[stbase + (size_t)e * NN2 + off] = f2bf(s[e]);
  }
}

// ---------------------------------------------------------------------------
// k_mode1c: C[q][m] = sum_j adj1t[q][j] * st[m][j]   (m = slice*16+e)
// out[slice][q][e] = relu(rb + C).  A,B GLDS16-staged, 2-phase pipeline,
// T14 rb pre-stage into Rs.  (unchanged from R8)
// ---------------------------------------------------------------------------
__global__ __launch_bounds__(256)
void k_mode1c(const ushort* __restrict__ A1t, const ushort* __restrict__ st,
              const ushort* __restrict__ rb, float* __restrict__ out) {
  __shared__ ushort As[2][4096];
  __shared__ ushort Bs[2][4096];
  __shared__ ushort Rs[16384];     // 8 sl x 128 q x 16 e

  const int t = threadIdx.x;
  const int lane = t & 63;
  const int wid = t >> 6;
  const int wm = wid >> 1, wn = wid & 1;
  const int q0  = blockIdx.x << 7;
  const int m0  = blockIdx.y << 7;
  const int sl0 = blockIdx.y << 3;

#pragma unroll
  for (int k = 0; k < 8; ++k) {
    const ushort* gsrc = rb + (size_t)(sl0 + k) * NCOL + q0 * 16 + (wid * 64 + lane) * 8;
    GLDS16(gsrc, &Rs[k * 2048 + wid * 512]);
  }

  f32x4 acc[4][4];
#pragma unroll
  for (int i = 0; i < 4; ++i)
#pragma unroll
    for (int j = 0; j < 4; ++j) acc[i][j] = (f32x4)0.f;

  const int srow = wid * 32 + (lane >> 2);
  const int schk = (lane & 3) * 8;
  const size_t aoff0 = (size_t)(q0 + srow) * 256 + schk;
  const size_t boff0 = (size_t)(m0 + srow) * 256 + schk;
  const int lw0 = (wid * 32) * 32;
  const int lw1 = (wid * 32 + 16) * 32;

  const int lm = lane & 15, g = lane >> 4;
  int aro[4], bro[4];
#pragma unroll
  for (int f = 0; f < 4; ++f) {
    const int ra = wm * 64 + f * 16 + lm;
    aro[f] = ra * 32 + ((g ^ ((ra >> 1) & 3)) << 3);
    const int rw = wn * 64 + f * 16 + lm;
    bro[f] = rw * 32 + ((g ^ ((rw >> 1) & 3)) << 3);
  }

#define STAGE1(buf, kk)                                                    \
  do {                                                                     \
    GLDS16(A1t + aoff0 + (kk), &As[buf][lw0]);                             \
    GLDS16(A1t + aoff0 + 16 * 256 + (kk), &As[buf][lw1]);                  \
    GLDS16(st + boff0 + (kk), &Bs[buf][lw0]);                              \
    GLDS16(st + boff0 + 16 * 256 + (kk), &Bs[buf][lw1]);                   \
  } while (0)

  STAGE1(0, 0);
  int cur = 0;

  for (int k0 = 0; k0 < 256; k0 += 32) {
    if (k0 + 32 < 256) {
      STAGE1(cur ^ 1, k0 + 32);
      asm volatile("s_waitcnt vmcnt(4)" ::: "memory");
    } else {
      asm volatile("s_waitcnt vmcnt(0)" ::: "memory");
    }
    __builtin_amdgcn_s_barrier();
    __builtin_amdgcn_sched_barrier(0);

    bf16x8 af[4], bfr[4];
#pragma unroll
    for (int f = 0; f < 4; ++f)
      af[f] = *reinterpret_cast<const bf16x8*>(&As[cur][aro[f]]);
#pragma unroll
    for (int f = 0; f < 4; ++f)
      bfr[f] = *reinterpret_cast<const bf16x8*>(&Bs[cur][bro[f]]);

#pragma unroll
    for (int i = 0; i < 4; ++i)
#pragma unroll
      for (int j = 0; j < 4; ++j)
        acc[i][j] = __builtin_amdgcn_mfma_f32_16x16x32_bf16(af[i], bfr[j], acc[i][j], 0, 0, 0);

    __builtin_amdgcn_sched_barrier(0);
    __builtin_amdgcn_s_barrier();
    cur ^= 1;
  }
#undef STAGE1

  const int orow = g * 4;
#pragma unroll
  for (int i = 0; i < 4; ++i)
#pragma unroll
    for (int j = 0; j < 4; ++j) {
      const int ml  = wn * 64 + j * 16 + lm;
      const int bpl = ml >> 4, e = ml & 15;
      const int ql  = wm * 64 + i * 16 + orow;
      const ushort* rsl = &Rs[bpl * 2048 + ql * 16 + e];
      float* dst = out + (size_t)(sl0 + bpl) * NCOL + (size_t)(q0 + ql) * EE + e;
#pragma unroll
      for (int r = 0; r < 4; ++r)
        dst[r * EE] = fmaxf(bf2f(rsl[r * 16]) + acc[i][j][r], 0.f);
    }
}

// ---------------------------------------------------------------------------
extern "C" void kernel_launch(void* const* d_in, const int* in_sizes, int n_in,
                              void* d_out, int out_size, void* d_ws, size_t ws_size,
                              hipStream_t stream) {
  const float* x    = (const float*)d_in[0];
  const float* adj0 = (const float*)d_in[1];
  const float* adj1 = (const float*)d_in[2];
  const float* W    = (const float*)d_in[3];
  const float* bW   = (const float*)d_in[4];
  const float* Ws0  = (const float*)d_in[5];
  const float* bs0  = (const float*)d_in[6];
  const float* Ws1  = (const float*)d_in[7];
  const float* bs1  = (const float*)d_in[8];
  const float* Ws01 = (const float*)d_in[9];
  const float* bs01 = (const float*)d_in[10];
  float* out = (float*)d_out;

  const size_t SLICE = (size_t)NN1 * NCOL;
  const size_t AT_B  = (size_t)1024 * 1024 * 2;
  const size_t A1T_B = (size_t)256 * 256 * 2;
  const size_t XT_B  = (size_t)NCOL * 1024 * 2;
  const size_t Y0_B  = SLICE * 2;
  const size_t ST_B  = SLICE * 2;
  const size_t RB_B  = SLICE * 2;
  const size_t HEAD  = AT_B + A1T_B;
  const size_t PER_B = XT_B + Y0_B + ST_B + RB_B;

  int nb_max = (int)((ws_size > HEAD ? ws_size - HEAD : 0) / PER_B);
  if (nb_max > BB) nb_max = BB;
  if (nb_max < 1)  nb_max = 1;

  ushort* At  = (ushort*)d_ws;
  ushort* A1t = (ushort*)((char*)d_ws + AT_B);
  ushort* Xt  = (ushort*)((char*)d_ws + HEAD);
  ushort* y0  = (ushort*)((char*)d_ws + HEAD + (size_t)nb_max * XT_B);
  ushort* st  = (ushort*)((char*)d_ws + HEAD + (size_t)nb_max * (XT_B + Y0_B));
  ushort* rb  = (ushort*)((char*)d_ws + HEAD + (size_t)nb_max * (XT_B + Y0_B + ST_B));

  // At/Xt: chunk-swizzle + 128B pair-swap (8-phase mode0); A1t: chunk-swizzle only
  k_prep<<<dim3(16, 16, 1), 256, 0, stream>>>(adj0, At, 1024, 1024, 0, 0, 1);
  k_prep<<<dim3(4, 4, 1), 256, 0, stream>>>(adj1, A1t, 256, 256, 0, 0, 0);

  for (int c0 = 0; c0 < BB; c0 += nb_max) {
    const int nb = (BB - c0 < nb_max) ? (BB - c0) : nb_max;
    const float* xc = x   + (size_t)c0 * SLICE;
    float*       oc = out + (size_t)c0 * SLICE;

    k_prep<<<dim3(NCOL / 64, 16, nb), 256, 0, stream>>>(
        xc, Xt, NCOL, 1024, SLICE, (size_t)NCOL * 1024, 1);

    dim3 g1(nb * 64);
    k_mode0_mfma<<<g1, 512, 0, stream>>>(At, Xt, y0);

    k_proj<<<dim3(nb * NN1), 256, 0, stream>>>(xc, y0, st, rb, W, bW, Ws0, bs0,
                                               Ws1, bs1, Ws01, bs01);

    dim3 g2(2, nb * 128);
    k_mode1c<<<g2, 256, 0, stream>>>(A1t, st, rb, oc);
  }
}

// Round 11
// 447.789 us; speedup vs baseline: 1.0170x; 1.0170x over previous
//
#include <hip/hip_runtime.h>

#define BB  8
#define NN1 1024
#define NN2 256
#define DD  16
#define EE  16
#define NCOL (NN2 * DD)   // 4096

using bf16x8  = __attribute__((ext_vector_type(8))) short;
using f32x4   = __attribute__((ext_vector_type(4))) float;
using ushort8 = __attribute__((ext_vector_type(8))) unsigned short;

__device__ __forceinline__ ushort f2bf(float x) {
  unsigned u = __float_as_uint(x);
  unsigned r = (u + 0x7FFFu + ((u >> 16) & 1u)) >> 16;
  return (ushort)r;
}
__device__ __forceinline__ float bf2f(ushort u) {
  return __uint_as_float((unsigned)u << 16);
}
__device__ __forceinline__ unsigned pkbf(float a, float b) {
  return (unsigned)f2bf(a) | ((unsigned)f2bf(b) << 16);
}

#define GLDS16(g, l)                                                       \
  __builtin_amdgcn_global_load_lds(                                        \
      (const __attribute__((address_space(1))) void*)(g),                  \
      (__attribute__((address_space(3))) void*)(l), 16, 0, 0)

// ---------------------------------------------------------------------------
// k_prep: transpose + fp32->bf16 + swizzle.
//  ps=0: 16B-chunk XOR within 64B blocks, chunk g <- g ^ ((row>>1)&3)  (R8 path)
//  ps=1: full 3-bit chunk XOR within 128B blocks: chunk g <- g ^ (row&7)
//        (conflict-free for the 8-phase kernel's 128B LDS rows)
// src fp32 [kd(k)][nr], dst bf16 [nr][kd].
// ---------------------------------------------------------------------------
__global__ __launch_bounds__(256)
void k_prep(const float* __restrict__ src, ushort* __restrict__ dst,
            int nr, int kd, size_t srcBatch, size_t dstBatch, int ps) {
  __shared__ float tile[64][65];
  const int t = threadIdx.x;
  const int r0 = blockIdx.x * 64;
  const int k0 = blockIdx.y * 64;
  const float* s = src + (size_t)blockIdx.z * srcBatch;
  ushort* d = dst + (size_t)blockIdx.z * dstBatch;

#pragma unroll
  for (int it = 0; it < 4; ++it) {
    const int kr = it * 16 + (t >> 4);
    const int rc = (t & 15) * 4;
    float4 v = *reinterpret_cast<const float4*>(&s[(size_t)(k0 + kr) * nr + r0 + rc]);
    tile[kr][rc] = v.x; tile[kr][rc + 1] = v.y;
    tile[kr][rc + 2] = v.z; tile[kr][rc + 3] = v.w;
  }
  __syncthreads();

#pragma unroll
  for (int pass = 0; pass < 2; ++pass) {
    const int task = t + pass * 256;
    const int pr = task >> 3;
    const int gl = task & 7;          // 16B chunk within this 64-k span
    const int r = r0 + pr;
    int klb;
    if (ps) {
      klb = (gl ^ (r & 7)) * 8;       // 8-chunk XOR (128B block = 64 k)
    } else {
      const int f = (r >> 1) & 3;
      klb = (gl >> 2) * 32 + ((gl & 3) ^ f) * 8;
    }
    unsigned w[4];
#pragma unroll
    for (int e2 = 0; e2 < 4; ++e2)
      w[e2] = pkbf(tile[klb + e2 * 2][pr], tile[klb + e2 * 2 + 1][pr]);
    *reinterpret_cast<uint4*>(&d[(size_t)r * kd + k0 + gl * 8]) =
        *reinterpret_cast<const uint4*>(w);
  }
}

// ---------------------------------------------------------------------------
// k_mode0_mfma: y[b][p][c] = sum_k adj0[k][p] * X[b][k][c] -> bf16
// 256x256 tile, BK=64, 8 waves (2p x 4c), per-wave 128x64 output.
// 8-phase schedule (T3+T4+T5). Per phase: {issue 1 half-tile (2 GLDS16),
// vmcnt(6), barrier, 12 ds_read_b128, 16 MFMA in setprio(1)}.
// LDS rows 128B, chunk^(row&7) XOR swizzle (pre-applied in global by k_prep).
// ---------------------------------------------------------------------------
__global__ __launch_bounds__(512)
void k_mode0_mfma(const ushort* __restrict__ At, const ushort* __restrict__ Xt,
                  ushort* __restrict__ Y) {
  __shared__ ushort As[2][16384];   // [buf][256 rows x 64 k]
  __shared__ ushort Bs[2][16384];

  const int t = threadIdx.x;
  const int lane = t & 63;
  const int wid = t >> 6;           // 0..7
  const int wm = wid >> 2;          // p half
  const int wn = wid & 3;           // c quarter

  // XCD-chunked bijective swizzle (nwg = nb*64, always % 8 == 0)
  const int nwg = (int)gridDim.x;
  const int wg  = (int)blockIdx.x;
  const int orig = (wg & 7) * (nwg >> 3) + (wg >> 3);
  const int b  = orig >> 6;
  const int rem = orig & 63;
  const int c0 = (rem >> 2) << 8;
  const int p0 = (rem & 3) << 8;

  const ushort* Bb = Xt + (size_t)b * (NCOL * 1024);

  f32x4 acc[8][4];
#pragma unroll
  for (int i = 0; i < 8; ++i)
#pragma unroll
    for (int j = 0; j < 4; ++j) acc[i][j] = (f32x4)0.f;

  const int lm = lane & 15, g = lane >> 4;

  // fragment LDS offsets: logical chunk (ks*4+g) XOR (row&7), row*64 base
  int aoff2[8][2], boff2[4][2];
#pragma unroll
  for (int f = 0; f < 8; ++f) {
    const int ra = wm * 128 + f * 16 + lm;
#pragma unroll
    for (int ks = 0; ks < 2; ++ks)
      aoff2[f][ks] = ra * 64 + (((ks * 4 + g) ^ (ra & 7)) << 3);
  }
#pragma unroll
  for (int f = 0; f < 4; ++f) {
    const int rb = wn * 64 + f * 16 + lm;
#pragma unroll
    for (int ks = 0; ks < 2; ++ks)
      boff2[f][ks] = rb * 64 + (((ks * 4 + g) ^ (rb & 7)) << 3);
  }

#define STG_A(buf, kt, hA) do {                                            \
    { const int r0_ = (hA) * 64 + wid * 8;                                 \
      GLDS16(At + (size_t)(p0 + r0_ + (lane >> 3)) * 1024 + (kt) * 64 +    \
                 (lane & 7) * 8, &As[buf][r0_ * 64]); }                    \
    { const int r0_ = (hA) * 64 + 128 + wid * 8;                           \
      GLDS16(At + (size_t)(p0 + r0_ + (lane >> 3)) * 1024 + (kt) * 64 +    \
                 (lane & 7) * 8, &As[buf][r0_ * 64]); }                    \
  } while (0)

#define STG_B(buf, kt, hB) do {                                            \
    { const int r0_ = (wid >> 2) * 64 + (hB) * 32 + (wid & 3) * 8;         \
      GLDS16(Bb + (size_t)(c0 + r0_ + (lane >> 3)) * 1024 + (kt) * 64 +    \
                 (lane & 7) * 8, &Bs[buf][r0_ * 64]); }                    \
    { const int r0_ = (2 + (wid >> 2)) * 64 + (hB) * 32 + (wid & 3) * 8;   \
      GLDS16(Bb + (size_t)(c0 + r0_ + (lane >> 3)) * 1024 + (kt) * 64 +    \
                 (lane & 7) * 8, &Bs[buf][r0_ * 64]); }                    \
  } while (0)

#define VM6 asm volatile("s_waitcnt vmcnt(6)" ::: "memory")
#define VM4 asm volatile("s_waitcnt vmcnt(4)" ::: "memory")
#define VM2 asm volatile("s_waitcnt vmcnt(2)" ::: "memory")
#define VM0 asm volatile("s_waitcnt vmcnt(0)" ::: "memory")
#define NOWAIT ((void)0)
#define NOSTG  ((void)0)

#define PHASE(buf, qi, qj, STGSTMT, WAITSTMT) do {                         \
    STGSTMT;                                                               \
    WAITSTMT;                                                              \
    __builtin_amdgcn_s_barrier();                                          \
    __builtin_amdgcn_sched_barrier(0);                                     \
    bf16x8 a_[4][2], b_[2][2];                                             \
    _Pragma("unroll")                                                      \
    for (int i_ = 0; i_ < 4; ++i_)                                         \
      _Pragma("unroll")                                                    \
      for (int ks_ = 0; ks_ < 2; ++ks_)                                    \
        a_[i_][ks_] = *reinterpret_cast<const bf16x8*>(                    \
            &As[buf][aoff2[(qi) * 4 + i_][ks_]]);                          \
    _Pragma("unroll")                                                      \
    for (int j_ = 0; j_ < 2; ++j_)                                         \
      _Pragma("unroll")                                                    \
      for (int ks_ = 0; ks_ < 2; ++ks_)                                    \
        b_[j_][ks_] = *reinterpret_cast<const bf16x8*>(                    \
            &Bs[buf][boff2[(qj) * 2 + j_][ks_]]);                          \
    __builtin_amdgcn_s_setprio(1);                                         \
    _Pragma("unroll")                                                      \
    for (int ks_ = 0; ks_ < 2; ++ks_)                                      \
      _Pragma("unroll")                                                    \
      for (int i_ = 0; i_ < 4; ++i_)                                       \
        _Pragma("unroll")                                                  \
        for (int j_ = 0; j_ < 2; ++j_)                                     \
          acc[(qi) * 4 + i_][(qj) * 2 + j_] =                              \
              __builtin_amdgcn_mfma_f32_16x16x32_bf16(                     \
                  a_[i_][ks_], b_[j_][ks_],                                \
                  acc[(qi) * 4 + i_][(qj) * 2 + j_], 0, 0, 0);             \
    __builtin_amdgcn_s_setprio(0);                                         \
  } while (0)

  // prologue: tile 0 -> buf0, halves A0,B0,A1,B1 (8 loads)
  STG_A(0, 0, 0); STG_B(0, 0, 0); STG_A(0, 0, 1); STG_B(0, 0, 1);

  for (int it = 0; it < 8; ++it) {
    const int t1 = 2 * it + 1, t2 = 2 * it + 2;
    PHASE(0, 0, 0, STG_A(1, t1, 0), VM6);
    PHASE(0, 1, 0, STG_B(1, t1, 0), VM6);
    PHASE(0, 0, 1, STG_A(1, t1, 1), VM6);
    PHASE(0, 1, 1, STG_B(1, t1, 1), VM6);
    __builtin_amdgcn_s_barrier();
    if (it < 7) {
      PHASE(1, 0, 0, STG_A(0, t2, 0), VM6);
      PHASE(1, 1, 0, STG_B(0, t2, 0), VM6);
      PHASE(1, 0, 1, STG_A(0, t2, 1), VM6);
      PHASE(1, 1, 1, STG_B(0, t2, 1), VM6);
    } else {
      PHASE(1, 0, 0, NOSTG, VM4);
      PHASE(1, 1, 0, NOSTG, VM2);
      PHASE(1, 0, 1, NOSTG, VM0);
      PHASE(1, 1, 1, NOSTG, NOWAIT);
    }
    __builtin_amdgcn_s_barrier();
  }
#undef PHASE
#undef STG_A
#undef STG_B

  ushort* Yb = Y + (size_t)b * ((size_t)NN1 * NCOL);
  const int orow = g * 4;
#pragma unroll
  for (int i = 0; i < 8; ++i)
#pragma unroll
    for (int j = 0; j < 4; ++j) {
      const int p = p0 + wm * 128 + i * 16 + orow;
      const int c = c0 + wn * 64 + j * 16 + lm;
      ushort* dst = Yb + (size_t)p * NCOL + c;
#pragma unroll
      for (int e = 0; e < 4; ++e) dst[(size_t)e * NCOL] = f2bf(acc[i][j][e]);
    }
}

// ---------------------------------------------------------------------------
// k_proj: per (b,p) slice, thread j:
//   r[j,e] = x@W + y0@W_s0 + sum(bias)  -> rb (bf16, [slice][j][e])
//   s[j,e] = x@W_s1 + y0@W_s01          -> st (bf16, swizzled, [slice*16+e][j])
// ---------------------------------------------------------------------------
__global__ __launch_bounds__(256)
void k_proj(const float* __restrict__ x, const ushort* __restrict__ y0,
            ushort* __restrict__ st, ushort* __restrict__ rb,
            const float* __restrict__ W,   const float* __restrict__ bW,
            const float* __restrict__ W0,  const float* __restrict__ b0,
            const float* __restrict__ W1,  const float* __restrict__ b1,
            const float* __restrict__ W01, const float* __restrict__ b01) {
  __shared__ float sW[4][DD][EE];
  __shared__ float sbias[EE];

  const int t = threadIdx.x;
  {
    const int m = t >> 6;
    const int r = t & 63;
    const float* Wp = (m == 0) ? W : (m == 1) ? W0 : (m == 2) ? W1 : W01;
    reinterpret_cast<float4*>(&sW[m][0][0])[r] =
        reinterpret_cast<const float4*>(Wp)[r];
  }
  if (t < EE) sbias[t] = bW[t] + b0[t] + b1[t] + b01[t];
  __syncthreads();

  const size_t base = (size_t)blockIdx.x * NCOL + (size_t)t * DD;

  float xr[DD], yr[DD];
#pragma unroll
  for (int v = 0; v < 4; ++v)
    *reinterpret_cast<float4*>(&xr[v * 4]) =
        *reinterpret_cast<const float4*>(&x[base + v * 4]);
  {
    ushort8 ya = *reinterpret_cast<const ushort8*>(&y0[base]);
    ushort8 yb = *reinterpret_cast<const ushort8*>(&y0[base + 8]);
#pragma unroll
    for (int k = 0; k < 8; ++k) { yr[k] = bf2f(ya[k]); yr[8 + k] = bf2f(yb[k]); }
  }

  float r[EE], s[EE];
#pragma unroll
  for (int e = 0; e < EE; ++e) { r[e] = sbias[e]; s[e] = 0.f; }

#pragma unroll
  for (int d = 0; d < DD; ++d) {
    const float xd = xr[d], yd = yr[d];
#pragma unroll
    for (int e = 0; e < EE; ++e) {
      r[e] = fmaf(xd, sW[0][d][e], r[e]);
      r[e] = fmaf(yd, sW[1][d][e], r[e]);
      s[e] = fmaf(xd, sW[2][d][e], s[e]);
      s[e] = fmaf(yd, sW[3][d][e], s[e]);
    }
  }

  {
    ushort rw[16];
#pragma unroll
    for (int e = 0; e < EE; ++e) rw[e] = f2bf(r[e]);
    *reinterpret_cast<uint4*>(&rb[base])     = *reinterpret_cast<const uint4*>(&rw[0]);
    *reinterpret_cast<uint4*>(&rb[base + 8]) = *reinterpret_cast<const uint4*>(&rw[8]);
  }

  const size_t stbase = (size_t)blockIdx.x * (EE * NN2);
#pragma unroll
  for (int e = 0; e < EE; ++e) {
    const int f = (e >> 1) & 3;
    const int off = (t >> 5) * 32 + ((((t >> 3) & 3) ^ f) << 3) + (t & 7);
    st[stbase + (size_t)e * NN2 + off] = f2bf(s[e]);
  }
}

// ---------------------------------------------------------------------------
// k_mode1c: C[q][m] = sum_j adj1t[q][j] * st[m][j]   (m = slice*16+e)
// out[slice][q][e] = relu(rb + C).  Unchanged from R8.
// ---------------------------------------------------------------------------
__global__ __launch_bounds__(256)
void k_mode1c(const ushort* __restrict__ A1t, const ushort* __restrict__ st,
              const ushort* __restrict__ rb, float* __restrict__ out) {
  __shared__ ushort As[2][4096];
  __shared__ ushort Bs[2][4096];
  __shared__ ushort Rs[16384];

  const int t = threadIdx.x;
  const int lane = t & 63;
  const int wid = t >> 6;
  const int wm = wid >> 1, wn = wid & 1;
  const int q0  = blockIdx.x << 7;
  const int m0  = blockIdx.y << 7;
  const int sl0 = blockIdx.y << 3;

#pragma unroll
  for (int k = 0; k < 8; ++k) {
    const ushort* gsrc = rb + (size_t)(sl0 + k) * NCOL + q0 * 16 + (wid * 64 + lane) * 8;
    GLDS16(gsrc, &Rs[k * 2048 + wid * 512]);
  }

  f32x4 acc[4][4];
#pragma unroll
  for (int i = 0; i < 4; ++i)
#pragma unroll
    for (int j = 0; j < 4; ++j) acc[i][j] = (f32x4)0.f;

  const int srow = wid * 32 + (lane >> 2);
  const int schk = (lane & 3) * 8;
  const size_t aoff0 = (size_t)(q0 + srow) * 256 + schk;
  const size_t boff0 = (size_t)(m0 + srow) * 256 + schk;
  const int lw0 = (wid * 32) * 32;
  const int lw1 = (wid * 32 + 16) * 32;

  const int lm = lane & 15, g = lane >> 4;
  int aro[4], bro[4];
#pragma unroll
  for (int f = 0; f < 4; ++f) {
    const int ra = wm * 64 + f * 16 + lm;
    aro[f] = ra * 32 + ((g ^ ((ra >> 1) & 3)) << 3);
    const int rw = wn * 64 + f * 16 + lm;
    bro[f] = rw * 32 + ((g ^ ((rw >> 1) & 3)) << 3);
  }

#define STAGE1(buf, kk)                                                    \
  do {                                                                     \
    GLDS16(A1t + aoff0 + (kk), &As[buf][lw0]);                             \
    GLDS16(A1t + aoff0 + 16 * 256 + (kk), &As[buf][lw1]);                  \
    GLDS16(st + boff0 + (kk), &Bs[buf][lw0]);                              \
    GLDS16(st + boff0 + 16 * 256 + (kk), &Bs[buf][lw1]);                   \
  } while (0)

  STAGE1(0, 0);
  int cur = 0;

  for (int k0 = 0; k0 < 256; k0 += 32) {
    if (k0 + 32 < 256) {
      STAGE1(cur ^ 1, k0 + 32);
      asm volatile("s_waitcnt vmcnt(4)" ::: "memory");
    } else {
      asm volatile("s_waitcnt vmcnt(0)" ::: "memory");
    }
    __builtin_amdgcn_s_barrier();
    __builtin_amdgcn_sched_barrier(0);

    bf16x8 af[4], bfr[4];
#pragma unroll
    for (int f = 0; f < 4; ++f)
      af[f] = *reinterpret_cast<const bf16x8*>(&As[cur][aro[f]]);
#pragma unroll
    for (int f = 0; f < 4; ++f)
      bfr[f] = *reinterpret_cast<const bf16x8*>(&Bs[cur][bro[f]]);

#pragma unroll
    for (int i = 0; i < 4; ++i)
#pragma unroll
      for (int j = 0; j < 4; ++j)
        acc[i][j] = __builtin_amdgcn_mfma_f32_16x16x32_bf16(af[i], bfr[j], acc[i][j], 0, 0, 0);

    __builtin_amdgcn_sched_barrier(0);
    __builtin_amdgcn_s_barrier();
    cur ^= 1;
  }
#undef STAGE1

  const int orow = g * 4;
#pragma unroll
  for (int i = 0; i < 4; ++i)
#pragma unroll
    for (int j = 0; j < 4; ++j) {
      const int ml  = wn * 64 + j * 16 + lm;
      const int bpl = ml >> 4, e = ml & 15;
      const int ql  = wm * 64 + i * 16 + orow;
      const ushort* rsl = &Rs[bpl * 2048 + ql * 16 + e];
      float* dst = out + (size_t)(sl0 + bpl) * NCOL + (size_t)(q0 + ql) * EE + e;
#pragma unroll
      for (int r = 0; r < 4; ++r)
        dst[r * EE] = fmaxf(bf2f(rsl[r * 16]) + acc[i][j][r], 0.f);
    }
}

// ---------------------------------------------------------------------------
extern "C" void kernel_launch(void* const* d_in, const int* in_sizes, int n_in,
                              void* d_out, int out_size, void* d_ws, size_t ws_size,
                              hipStream_t stream) {
  const float* x    = (const float*)d_in[0];
  const float* adj0 = (const float*)d_in[1];
  const float* adj1 = (const float*)d_in[2];
  const float* W    = (const float*)d_in[3];
  const float* bW   = (const float*)d_in[4];
  const float* Ws0  = (const float*)d_in[5];
  const float* bs0  = (const float*)d_in[6];
  const float* Ws1  = (const float*)d_in[7];
  const float* bs1  = (const float*)d_in[8];
  const float* Ws01 = (const float*)d_in[9];
  const float* bs01 = (const float*)d_in[10];
  float* out = (float*)d_out;

  const size_t SLICE = (size_t)NN1 * NCOL;
  const size_t AT_B  = (size_t)1024 * 1024 * 2;
  const size_t A1T_B = (size_t)256 * 256 * 2;
  const size_t XT_B  = (size_t)NCOL * 1024 * 2;
  const size_t Y0_B  = SLICE * 2;
  const size_t ST_B  = SLICE * 2;
  const size_t RB_B  = SLICE * 2;
  const size_t HEAD  = AT_B + A1T_B;
  const size_t PER_B = XT_B + Y0_B + ST_B + RB_B;

  int nb_max = (int)((ws_size > HEAD ? ws_size - HEAD : 0) / PER_B);
  if (nb_max > BB) nb_max = BB;
  if (nb_max < 1)  nb_max = 1;

  ushort* At  = (ushort*)d_ws;
  ushort* A1t = (ushort*)((char*)d_ws + AT_B);
  ushort* Xt  = (ushort*)((char*)d_ws + HEAD);
  ushort* y0  = (ushort*)((char*)d_ws + HEAD + (size_t)nb_max * XT_B);
  ushort* st  = (ushort*)((char*)d_ws + HEAD + (size_t)nb_max * (XT_B + Y0_B));
  ushort* rb  = (ushort*)((char*)d_ws + HEAD + (size_t)nb_max * (XT_B + Y0_B + ST_B));

  k_prep<<<dim3(16, 16, 1), 256, 0, stream>>>(adj0, At, 1024, 1024, 0, 0, 1);
  k_prep<<<dim3(4, 4, 1), 256, 0, stream>>>(adj1, A1t, 256, 256, 0, 0, 0);

  for (int c0 = 0; c0 < BB; c0 += nb_max) {
    const int nb = (BB - c0 < nb_max) ? (BB - c0) : nb_max;
    const float* xc = x   + (size_t)c0 * SLICE;
    float*       oc = out + (size_t)c0 * SLICE;

    k_prep<<<dim3(NCOL / 64, 16, nb), 256, 0, stream>>>(
        xc, Xt, NCOL, 1024, SLICE, (size_t)NCOL * 1024, 1);

    dim3 g1(nb * 64);
    k_mode0_mfma<<<g1, 512, 0, stream>>>(At, Xt, y0);

    k_proj<<<dim3(nb * NN1), 256, 0, stream>>>(xc, y0, st, rb, W, bW, Ws0, bs0,
                                               Ws1, bs1, Ws01, bs01);

    dim3 g2(2, nb * 128);
    k_mode1c<<<g2, 256, 0, stream>>>(A1t, st, rb, oc);
  }
}

// Round 12
// 236.844 us; speedup vs baseline: 1.9229x; 1.8906x over previous
//
#include <hip/hip_runtime.h>

#define BB  8
#define NN1 1024
#define NN2 256
#define DD  16
#define EE  16
#define NCOL (NN2 * DD)   // 4096
#define SLPB 2            // slices per k_pm block

using bf16x8  = __attribute__((ext_vector_type(8))) short;
using f32x4   = __attribute__((ext_vector_type(4))) float;
using ushort8 = __attribute__((ext_vector_type(8))) unsigned short;

__device__ __forceinline__ ushort f2bf(float x) {
  unsigned u = __float_as_uint(x);
  unsigned r = (u + 0x7FFFu + ((u >> 16) & 1u)) >> 16;
  return (ushort)r;
}
__device__ __forceinline__ float bf2f(ushort u) {
  return __uint_as_float((unsigned)u << 16);
}
__device__ __forceinline__ unsigned pkbf(float a, float b) {
  return (unsigned)f2bf(a) | ((unsigned)f2bf(b) << 16);
}

#define GLDS16(g, l)                                                       \
  __builtin_amdgcn_global_load_lds(                                        \
      (const __attribute__((address_space(1))) void*)(g),                  \
      (__attribute__((address_space(3))) void*)(l), 16, 0, 0)

// ---------------------------------------------------------------------------
// k_prep: transpose + fp32->bf16 + 16B-chunk swizzle (R8 semantics):
// within each 64B block, chunk g <- g ^ ((row>>1)&3).
// src fp32 [kd(k)][nr], dst bf16 [nr][kd].
// ---------------------------------------------------------------------------
__global__ __launch_bounds__(256)
void k_prep(const float* __restrict__ src, ushort* __restrict__ dst,
            int nr, int kd, size_t srcBatch, size_t dstBatch) {
  __shared__ float tile[64][65];
  const int t = threadIdx.x;
  const int r0 = blockIdx.x * 64;
  const int k0 = blockIdx.y * 64;
  const float* s = src + (size_t)blockIdx.z * srcBatch;
  ushort* d = dst + (size_t)blockIdx.z * dstBatch;

#pragma unroll
  for (int it = 0; it < 4; ++it) {
    const int kr = it * 16 + (t >> 4);
    const int rc = (t & 15) * 4;
    float4 v = *reinterpret_cast<const float4*>(&s[(size_t)(k0 + kr) * nr + r0 + rc]);
    tile[kr][rc] = v.x; tile[kr][rc + 1] = v.y;
    tile[kr][rc + 2] = v.z; tile[kr][rc + 3] = v.w;
  }
  __syncthreads();

#pragma unroll
  for (int pass = 0; pass < 2; ++pass) {
    const int task = t + pass * 256;
    const int pr = task >> 3;
    const int gl = task & 7;
    const int r = r0 + pr;
    const int f = (r >> 1) & 3;
    const int klb = (gl >> 2) * 32 + ((gl & 3) ^ f) * 8;
    unsigned w[4];
#pragma unroll
    for (int e2 = 0; e2 < 4; ++e2)
      w[e2] = pkbf(tile[klb + e2 * 2][pr], tile[klb + e2 * 2 + 1][pr]);
    *reinterpret_cast<uint4*>(&d[(size_t)r * kd + k0 + gl * 8]) =
        *reinterpret_cast<const uint4*>(w);
  }
}

// ---------------------------------------------------------------------------
// k_mode0_mfma: y[b][p][c] = sum_k adj0[k][p] * X[b][k][c] -> bf16
// R8-exact: 128x128 tile, BK=32, 4 waves 64x64, 2-phase, vmcnt(4).
// ---------------------------------------------------------------------------
__global__ __launch_bounds__(256)
void k_mode0_mfma(const ushort* __restrict__ At, const ushort* __restrict__ Xt,
                  ushort* __restrict__ Y) {
  __shared__ ushort As[2][4096];
  __shared__ ushort Bs[2][4096];

  const int t = threadIdx.x;
  const int lane = t & 63;
  const int wid = t >> 6;
  const int wm = wid >> 1, wn = wid & 1;
  const int b  = blockIdx.x >> 5;
  const int c0 = (blockIdx.x & 31) << 7;
  const int p0 = blockIdx.y << 7;

  const ushort* Bb = Xt + (size_t)b * (NCOL * 1024);

  f32x4 acc[4][4];
#pragma unroll
  for (int i = 0; i < 4; ++i)
#pragma unroll
    for (int j = 0; j < 4; ++j) acc[i][j] = (f32x4)0.f;

  const int srow = wid * 32 + (lane >> 2);
  const int schk = (lane & 3) * 8;
  const size_t aoff0 = (size_t)(p0 + srow) * 1024 + schk;
  const size_t boff0 = (size_t)(c0 + srow) * 1024 + schk;
  const int lw0 = (wid * 32) * 32;
  const int lw1 = (wid * 32 + 16) * 32;

  const int lm = lane & 15, g = lane >> 4;
  int aro[4], bro[4];
#pragma unroll
  for (int f = 0; f < 4; ++f) {
    const int ra = wm * 64 + f * 16 + lm;
    aro[f] = ra * 32 + ((g ^ ((ra >> 1) & 3)) << 3);
    const int rw = wn * 64 + f * 16 + lm;
    bro[f] = rw * 32 + ((g ^ ((rw >> 1) & 3)) << 3);
  }

#define STAGE0(buf, kk)                                                    \
  do {                                                                     \
    GLDS16(At + aoff0 + (kk), &As[buf][lw0]);                              \
    GLDS16(At + aoff0 + 16 * 1024 + (kk), &As[buf][lw1]);                  \
    GLDS16(Bb + boff0 + (kk), &Bs[buf][lw0]);                              \
    GLDS16(Bb + boff0 + 16 * 1024 + (kk), &Bs[buf][lw1]);                  \
  } while (0)

  STAGE0(0, 0);
  int cur = 0;

  for (int k0 = 0; k0 < 1024; k0 += 32) {
    if (k0 + 32 < 1024) {
      STAGE0(cur ^ 1, k0 + 32);
      asm volatile("s_waitcnt vmcnt(4)" ::: "memory");
    } else {
      asm volatile("s_waitcnt vmcnt(0)" ::: "memory");
    }
    __builtin_amdgcn_s_barrier();
    __builtin_amdgcn_sched_barrier(0);

    bf16x8 af[4], bfr[4];
#pragma unroll
    for (int f = 0; f < 4; ++f)
      af[f] = *reinterpret_cast<const bf16x8*>(&As[cur][aro[f]]);
#pragma unroll
    for (int f = 0; f < 4; ++f)
      bfr[f] = *reinterpret_cast<const bf16x8*>(&Bs[cur][bro[f]]);

#pragma unroll
    for (int i = 0; i < 4; ++i)
#pragma unroll
      for (int j = 0; j < 4; ++j)
        acc[i][j] = __builtin_amdgcn_mfma_f32_16x16x32_bf16(af[i], bfr[j], acc[i][j], 0, 0, 0);

    __builtin_amdgcn_sched_barrier(0);
    __builtin_amdgcn_s_barrier();
    cur ^= 1;
  }
#undef STAGE0

  ushort* Yb = Y + (size_t)b * (NN1 * NCOL);
  const int orow = g * 4;
  const int ocol = lm;
#pragma unroll
  for (int i = 0; i < 4; ++i)
#pragma unroll
    for (int j = 0; j < 4; ++j) {
      const int p = p0 + wm * 64 + i * 16 + orow;
      const int c = c0 + wn * 64 + j * 16 + ocol;
      ushort* dst = Yb + (size_t)p * NCOL + c;
#pragma unroll
      for (int e = 0; e < 4; ++e) dst[(size_t)e * NCOL] = f2bf(acc[i][j][e]);
    }
}

// ---------------------------------------------------------------------------
// k_pm: fused projection + mode1 per SLPB slices (512 threads, 2 blocks/CU).
// Phase 1 (k_proj math, 1 row/thread):
//   r[j,e] -> Rb LDS (bf16, [sl][j][24-pitch]); s[j,e] -> St LDS
//   (bf16, [kc][m=sl*16+e][32], 16B-chunk XOR == mode1c Bs layout)
// Phase 2 (mode1c GEMM): C[q][m] = sum_j adj1t[q][j]*St[m][j]; A1t GLDS16
//   double-buffered, counted vmcnt(2); out = relu(Rb + C), single write.
// ---------------------------------------------------------------------------
__global__ __launch_bounds__(512)
void k_pm(const float* __restrict__ x, const ushort* __restrict__ y0,
          const ushort* __restrict__ A1t,
          const float* __restrict__ W,   const float* __restrict__ bW,
          const float* __restrict__ W0,  const float* __restrict__ b0,
          const float* __restrict__ W1,  const float* __restrict__ b1,
          const float* __restrict__ W01, const float* __restrict__ b01,
          float* __restrict__ out) {
  __shared__ float sW[4][DD][EE];                  // 4 KB
  __shared__ float sbias[EE];
  __shared__ ushort St[8][SLPB * 16][32];          // 16 KB
  __shared__ ushort Rb[SLPB][256][24];             // 24 KB (pitch 24 = 48B)
  __shared__ ushort As[2][256 * 32];               // 32 KB

  const int t = threadIdx.x;
  const int lane = t & 63;
  const int wid = t >> 6;                          // 0..7
  const size_t sl0 = (size_t)blockIdx.x * SLPB;

  // A1t staging geometry (mode1c-style; dest base is wave-uniform)
  const int srow = wid * 32 + (lane >> 2);
  const int schk = (lane & 3) * 8;

#define STAGEA(buf, kc)                                                    \
  do {                                                                     \
    GLDS16(A1t + (size_t)srow * 256 + (kc) * 32 + schk,                    \
           &As[buf][(wid * 32) * 32]);                                     \
    GLDS16(A1t + (size_t)(srow + 16) * 256 + (kc) * 32 + schk,             \
           &As[buf][(wid * 32 + 16) * 32]);                                \
  } while (0)

  // T14: issue kchunk-0 A1t stage before phase 1 (lands under proj work)
  STAGEA(0, 0);

  // ---- phase 1: projection (k_proj math, 1 row/thread) ----
  {
    const int m = t >> 6;
    const int r = t & 63;
    if (t < 256) {
      const float* Wp = (m == 0) ? W : (m == 1) ? W0 : (m == 2) ? W1 : W01;
      reinterpret_cast<float4*>(&sW[m][0][0])[r] =
          reinterpret_cast<const float4*>(Wp)[r];
    }
    if (t < EE) sbias[t] = bW[t] + b0[t] + b1[t] + b01[t];
  }

  const int sl = t >> 8;            // 0..1
  const int j  = t & 255;
  const size_t base = (sl0 + sl) * NCOL + (size_t)j * DD;

  float xr[DD], yr[DD];
#pragma unroll
  for (int v = 0; v < 4; ++v)
    *reinterpret_cast<float4*>(&xr[v * 4]) =
        *reinterpret_cast<const float4*>(&x[base + v * 4]);
  {
    ushort8 ya = *reinterpret_cast<const ushort8*>(&y0[base]);
    ushort8 yb = *reinterpret_cast<const ushort8*>(&y0[base + 8]);
#pragma unroll
    for (int k = 0; k < 8; ++k) { yr[k] = bf2f(ya[k]); yr[8 + k] = bf2f(yb[k]); }
  }

  __syncthreads();   // sW/sbias ready (also drains prologue loads; harmless)

  float r[EE], s[EE];
#pragma unroll
  for (int e = 0; e < EE; ++e) { r[e] = sbias[e]; s[e] = 0.f; }

#pragma unroll
  for (int d = 0; d < DD; ++d) {
    const float xd = xr[d], yd = yr[d];
#pragma unroll
    for (int e = 0; e < EE; ++e) {
      r[e] = fmaf(xd, sW[0][d][e], r[e]);
      r[e] = fmaf(yd, sW[1][d][e], r[e]);
      s[e] = fmaf(xd, sW[2][d][e], s[e]);
      s[e] = fmaf(yd, sW[3][d][e], s[e]);
    }
  }

  // r -> Rb LDS (bf16, 2x uint4, 48B row pitch keeps 16B alignment)
  {
    ushort rw[16];
#pragma unroll
    for (int e = 0; e < EE; ++e) rw[e] = f2bf(r[e]);
    *reinterpret_cast<uint4*>(&Rb[sl][j][0]) = *reinterpret_cast<const uint4*>(&rw[0]);
    *reinterpret_cast<uint4*>(&Rb[sl][j][8]) = *reinterpret_cast<const uint4*>(&rw[8]);
  }

  // s -> St LDS, mode1c Bs layout: row m = sl*16+e, kchunk kc = j>>5,
  // phys chunk = (jj>>3) ^ ((m>>1)&3), position jj&7
  {
    const int kc = j >> 5;
    const int jj = j & 31;
#pragma unroll
    for (int e = 0; e < EE; ++e) {
      const int m = sl * 16 + e;
      const int idx = (((jj >> 3) ^ ((m >> 1) & 3)) << 3) + (jj & 7);
      St[kc][m][idx] = f2bf(s[e]);
    }
  }

  __syncthreads();   // St/Rb complete before GEMM

  // ---- phase 2: mode1 GEMM (mode1c loop structure) ----
  const int lm = lane & 15, g = lane >> 4;
  const int wq  = wid >> 1;         // 0..3 : 64-q stripe
  const int wmi = wid & 1;          // 0..1 : 16-m stripe (= slice)

  int aro[4];
#pragma unroll
  for (int f = 0; f < 4; ++f) {
    const int ra = wq * 64 + f * 16 + lm;
    aro[f] = ra * 32 + ((g ^ ((ra >> 1) & 3)) << 3);
  }
  const int rwB = wmi * 16 + lm;
  const int bofs = (rwB * 32) + ((g ^ ((rwB >> 1) & 3)) << 3);

  f32x4 acc[4];
#pragma unroll
  for (int i = 0; i < 4; ++i) acc[i] = (f32x4)0.f;

  int cur = 0;
  for (int kc = 0; kc < 8; ++kc) {
    if (kc < 7) {
      STAGEA(cur ^ 1, kc + 1);
      asm volatile("s_waitcnt vmcnt(2)" ::: "memory");
    } else {
      asm volatile("s_waitcnt vmcnt(0)" ::: "memory");
    }
    __builtin_amdgcn_s_barrier();
    __builtin_amdgcn_sched_barrier(0);

    bf16x8 af[4];
#pragma unroll
    for (int f = 0; f < 4; ++f)
      af[f] = *reinterpret_cast<const bf16x8*>(&As[cur][aro[f]]);
    const bf16x8 bfr = *reinterpret_cast<const bf16x8*>(&St[kc][0][0] + bofs);

#pragma unroll
    for (int i = 0; i < 4; ++i)
      acc[i] = __builtin_amdgcn_mfma_f32_16x16x32_bf16(af[i], bfr, acc[i], 0, 0, 0);

    __builtin_amdgcn_sched_barrier(0);
    __builtin_amdgcn_s_barrier();
    cur ^= 1;
  }
#undef STAGEA

  // ---- epilogue: out = relu(Rb + C), single fp32 write ----
  float* os = out + (sl0 + wmi) * NCOL;
#pragma unroll
  for (int i = 0; i < 4; ++i) {
    const int qb = wq * 64 + i * 16 + g * 4;
#pragma unroll
    for (int rr = 0; rr < 4; ++rr) {
      const int q = qb + rr;
      os[(size_t)q * EE + lm] =
          fmaxf(bf2f(Rb[wmi][q][lm]) + acc[i][rr], 0.f);
    }
  }
}

// ---------------------------------------------------------------------------
extern "C" void kernel_launch(void* const* d_in, const int* in_sizes, int n_in,
                              void* d_out, int out_size, void* d_ws, size_t ws_size,
                              hipStream_t stream) {
  const float* x    = (const float*)d_in[0];
  const float* adj0 = (const float*)d_in[1];
  const float* adj1 = (const float*)d_in[2];
  const float* W    = (const float*)d_in[3];
  const float* bW   = (const float*)d_in[4];
  const float* Ws0  = (const float*)d_in[5];
  const float* bs0  = (const float*)d_in[6];
  const float* Ws1  = (const float*)d_in[7];
  const float* bs1  = (const float*)d_in[8];
  const float* Ws01 = (const float*)d_in[9];
  const float* bs01 = (const float*)d_in[10];
  float* out = (float*)d_out;

  const size_t SLICE = (size_t)NN1 * NCOL;
  const size_t AT_B  = (size_t)1024 * 1024 * 2;      // adj0^T bf16 swz
  const size_t A1T_B = (size_t)256 * 256 * 2;        // adj1^T bf16 swz
  const size_t XT_B  = (size_t)NCOL * 1024 * 2;      // per-batch, 8.4 MB
  const size_t Y0_B  = SLICE * 2;                    // per-batch bf16
  const size_t HEAD  = AT_B + A1T_B;
  const size_t PER_B = XT_B + Y0_B;

  int nb_max = (int)((ws_size > HEAD ? ws_size - HEAD : 0) / PER_B);
  if (nb_max > BB) nb_max = BB;
  if (nb_max < 1)  nb_max = 1;

  ushort* At  = (ushort*)d_ws;
  ushort* A1t = (ushort*)((char*)d_ws + AT_B);
  ushort* Xt  = (ushort*)((char*)d_ws + HEAD);
  ushort* y0  = (ushort*)((char*)d_ws + HEAD + (size_t)nb_max * XT_B);

  k_prep<<<dim3(16, 16, 1), 256, 0, stream>>>(adj0, At, 1024, 1024, 0, 0);
  k_prep<<<dim3(4, 4, 1), 256, 0, stream>>>(adj1, A1t, 256, 256, 0, 0);

  for (int c0 = 0; c0 < BB; c0 += nb_max) {
    const int nb = (BB - c0 < nb_max) ? (BB - c0) : nb_max;
    const float* xc = x   + (size_t)c0 * SLICE;
    float*       oc = out + (size_t)c0 * SLICE;

    k_prep<<<dim3(NCOL / 64, 16, nb), 256, 0, stream>>>(
        xc, Xt, NCOL, 1024, SLICE, (size_t)NCOL * 1024);

    dim3 g1(nb * 32, 8);
    k_mode0_mfma<<<g1, 256, 0, stream>>>(At, Xt, y0);

    dim3 g2(nb * NN1 / SLPB);
    k_pm<<<g2, 512, 0, stream>>>(xc, y0, A1t, W, bW, Ws0, bs0,
                                 Ws1, bs1, Ws01, bs01, oc);
  }
}

// Round 13
// 207.982 us; speedup vs baseline: 2.1897x; 1.1388x over previous
//
#include <hip/hip_runtime.h>

#define BB  8
#define NN1 1024
#define NN2 256
#define DD  16
#define EE  16
#define NCOL (NN2 * DD)   // 4096
#define SLPB 2            // slices per k_pm block

using bf16x8  = __attribute__((ext_vector_type(8))) short;
using f32x4   = __attribute__((ext_vector_type(4))) float;
using ushort8 = __attribute__((ext_vector_type(8))) unsigned short;

__device__ __forceinline__ ushort f2bf(float x) {
  unsigned u = __float_as_uint(x);
  unsigned r = (u + 0x7FFFu + ((u >> 16) & 1u)) >> 16;
  return (ushort)r;
}
__device__ __forceinline__ float bf2f(ushort u) {
  return __uint_as_float((unsigned)u << 16);
}
__device__ __forceinline__ unsigned pkbf(float a, float b) {
  return (unsigned)f2bf(a) | ((unsigned)f2bf(b) << 16);
}

#define GLDS16(g, l)                                                       \
  __builtin_amdgcn_global_load_lds(                                        \
      (const __attribute__((address_space(1))) void*)(g),                  \
      (__attribute__((address_space(3))) void*)(l), 16, 0, 0)

// ---------------------------------------------------------------------------
// k_prep: transpose + fp32->bf16 + 16B-chunk swizzle (R8 semantics):
// within each 64B block, chunk g <- g ^ ((row>>1)&3).
// src fp32 [kd(k)][nr], dst bf16 [nr][kd].
// ---------------------------------------------------------------------------
__global__ __launch_bounds__(256)
void k_prep(const float* __restrict__ src, ushort* __restrict__ dst,
            int nr, int kd, size_t srcBatch, size_t dstBatch) {
  __shared__ float tile[64][65];
  const int t = threadIdx.x;
  const int r0 = blockIdx.x * 64;
  const int k0 = blockIdx.y * 64;
  const float* s = src + (size_t)blockIdx.z * srcBatch;
  ushort* d = dst + (size_t)blockIdx.z * dstBatch;

#pragma unroll
  for (int it = 0; it < 4; ++it) {
    const int kr = it * 16 + (t >> 4);
    const int rc = (t & 15) * 4;
    float4 v = *reinterpret_cast<const float4*>(&s[(size_t)(k0 + kr) * nr + r0 + rc]);
    tile[kr][rc] = v.x; tile[kr][rc + 1] = v.y;
    tile[kr][rc + 2] = v.z; tile[kr][rc + 3] = v.w;
  }
  __syncthreads();

#pragma unroll
  for (int pass = 0; pass < 2; ++pass) {
    const int task = t + pass * 256;
    const int pr = task >> 3;
    const int gl = task & 7;
    const int r = r0 + pr;
    const int f = (r >> 1) & 3;
    const int klb = (gl >> 2) * 32 + ((gl & 3) ^ f) * 8;
    unsigned w[4];
#pragma unroll
    for (int e2 = 0; e2 < 4; ++e2)
      w[e2] = pkbf(tile[klb + e2 * 2][pr], tile[klb + e2 * 2 + 1][pr]);
    *reinterpret_cast<uint4*>(&d[(size_t)r * kd + k0 + gl * 8]) =
        *reinterpret_cast<const uint4*>(w);
  }
}

// ---------------------------------------------------------------------------
// k_mode0_mfma: y[b][p][c] = sum_k adj0[k][p] * X[b][k][c] -> bf16
// R8-exact: 128x128 tile, BK=32, 4 waves 64x64, 2-phase, vmcnt(4).
// ---------------------------------------------------------------------------
__global__ __launch_bounds__(256)
void k_mode0_mfma(const ushort* __restrict__ At, const ushort* __restrict__ Xt,
                  ushort* __restrict__ Y) {
  __shared__ ushort As[2][4096];
  __shared__ ushort Bs[2][4096];

  const int t = threadIdx.x;
  const int lane = t & 63;
  const int wid = t >> 6;
  const int wm = wid >> 1, wn = wid & 1;
  const int b  = blockIdx.x >> 5;
  const int c0 = (blockIdx.x & 31) << 7;
  const int p0 = blockIdx.y << 7;

  const ushort* Bb = Xt + (size_t)b * (NCOL * 1024);

  f32x4 acc[4][4];
#pragma unroll
  for (int i = 0; i < 4; ++i)
#pragma unroll
    for (int j = 0; j < 4; ++j) acc[i][j] = (f32x4)0.f;

  const int srow = wid * 32 + (lane >> 2);
  const int schk = (lane & 3) * 8;
  const size_t aoff0 = (size_t)(p0 + srow) * 1024 + schk;
  const size_t boff0 = (size_t)(c0 + srow) * 1024 + schk;
  const int lw0 = (wid * 32) * 32;
  const int lw1 = (wid * 32 + 16) * 32;

  const int lm = lane & 15, g = lane >> 4;
  int aro[4], bro[4];
#pragma unroll
  for (int f = 0; f < 4; ++f) {
    const int ra = wm * 64 + f * 16 + lm;
    aro[f] = ra * 32 + ((g ^ ((ra >> 1) & 3)) << 3);
    const int rw = wn * 64 + f * 16 + lm;
    bro[f] = rw * 32 + ((g ^ ((rw >> 1) & 3)) << 3);
  }

#define STAGE0(buf, kk)                                                    \
  do {                                                                     \
    GLDS16(At + aoff0 + (kk), &As[buf][lw0]);                              \
    GLDS16(At + aoff0 + 16 * 1024 + (kk), &As[buf][lw1]);                  \
    GLDS16(Bb + boff0 + (kk), &Bs[buf][lw0]);                              \
    GLDS16(Bb + boff0 + 16 * 1024 + (kk), &Bs[buf][lw1]);                  \
  } while (0)

  STAGE0(0, 0);
  int cur = 0;

  for (int k0 = 0; k0 < 1024; k0 += 32) {
    if (k0 + 32 < 1024) {
      STAGE0(cur ^ 1, k0 + 32);
      asm volatile("s_waitcnt vmcnt(4)" ::: "memory");
    } else {
      asm volatile("s_waitcnt vmcnt(0)" ::: "memory");
    }
    __builtin_amdgcn_s_barrier();
    __builtin_amdgcn_sched_barrier(0);

    bf16x8 af[4], bfr[4];
#pragma unroll
    for (int f = 0; f < 4; ++f)
      af[f] = *reinterpret_cast<const bf16x8*>(&As[cur][aro[f]]);
#pragma unroll
    for (int f = 0; f < 4; ++f)
      bfr[f] = *reinterpret_cast<const bf16x8*>(&Bs[cur][bro[f]]);

#pragma unroll
    for (int i = 0; i < 4; ++i)
#pragma unroll
      for (int j = 0; j < 4; ++j)
        acc[i][j] = __builtin_amdgcn_mfma_f32_16x16x32_bf16(af[i], bfr[j], acc[i][j], 0, 0, 0);

    __builtin_amdgcn_sched_barrier(0);
    __builtin_amdgcn_s_barrier();
    cur ^= 1;
  }
#undef STAGE0

  ushort* Yb = Y + (size_t)b * (NN1 * NCOL);
  const int orow = g * 4;
  const int ocol = lm;
#pragma unroll
  for (int i = 0; i < 4; ++i)
#pragma unroll
    for (int j = 0; j < 4; ++j) {
      const int p = p0 + wm * 64 + i * 16 + orow;
      const int c = c0 + wn * 64 + j * 16 + ocol;
      ushort* dst = Yb + (size_t)p * NCOL + c;
#pragma unroll
      for (int e = 0; e < 4; ++e) dst[(size_t)e * NCOL] = f2bf(acc[i][j][e]);
    }
}

// ---------------------------------------------------------------------------
// k_pm: fused projection(MFMA) + mode1 per SLPB slices (512 thr).
// Phase 1: x,y0 -> X/Y LDS (union with As); per wave, 4 groups i:
//   acc[i] = mfma([x|y0], [W;W_s0], bias)   (r stays in the accumulator)
//   s      = mfma([x|y0], [W_s1;W_s01], 0) -> St LDS (mode1c Bs layout)
// Wave (wq,wmi) owns groups wmi*16+wq*4+i so proj D rows == mode1 q rows.
// Phase 2: acc[i] += sum_kc mfma(A1t_frag, St_frag); out = relu(acc).
// ---------------------------------------------------------------------------
__global__ __launch_bounds__(512)
void k_pm(const float* __restrict__ x, const ushort* __restrict__ y0,
          const ushort* __restrict__ A1t,
          const float* __restrict__ W,   const float* __restrict__ bW,
          const float* __restrict__ W0,  const float* __restrict__ b0,
          const float* __restrict__ W1,  const float* __restrict__ b1,
          const float* __restrict__ W01, const float* __restrict__ b01,
          float* __restrict__ out) {
  __shared__ ushort As[2][8192];     // 32 KB; phase1: As[0]=X rows, As[1]=Y rows
  __shared__ ushort St[8][SLPB * 16][32];   // 16 KB

  const int t = threadIdx.x;
  const int lane = t & 63;
  const int wid = t >> 6;            // 0..7
  const int lm = lane & 15, g = lane >> 4;
  const int wq  = wid >> 1;          // 0..3 : 64-q stripe
  const int wmi = wid & 1;           // 0..1 : slice
  const size_t sl0 = (size_t)blockIdx.x * SLPB;

  // ---- phase 1a: stage x (convert) and y0 rows into X/Y LDS ----
  {
    const size_t base = (sl0 * NCOL) + (size_t)t * DD;   // row j_global = t
    const float4 x0 = *reinterpret_cast<const float4*>(&x[base]);
    const float4 x1 = *reinterpret_cast<const float4*>(&x[base + 4]);
    const float4 x2 = *reinterpret_cast<const float4*>(&x[base + 8]);
    const float4 x3 = *reinterpret_cast<const float4*>(&x[base + 12]);
    const uint4 yv0 = *reinterpret_cast<const uint4*>(&y0[base]);
    const uint4 yv1 = *reinterpret_cast<const uint4*>(&y0[base + 8]);
    unsigned xw0[4] = {pkbf(x0.x, x0.y), pkbf(x0.z, x0.w), pkbf(x1.x, x1.y), pkbf(x1.z, x1.w)};
    unsigned xw1[4] = {pkbf(x2.x, x2.y), pkbf(x2.z, x2.w), pkbf(x3.x, x3.y), pkbf(x3.z, x3.w)};
    *reinterpret_cast<uint4*>(&As[0][t * 16])     = *reinterpret_cast<const uint4*>(xw0);
    *reinterpret_cast<uint4*>(&As[0][t * 16 + 8]) = *reinterpret_cast<const uint4*>(xw1);
    *reinterpret_cast<uint4*>(&As[1][t * 16])     = yv0;
    *reinterpret_cast<uint4*>(&As[1][t * 16 + 8]) = yv1;
  }

  // ---- W fragments + bias (R6-verified mapping: k = g*8+jj over [x|y0]) ----
  bf16x8 wfr, wfs;
#pragma unroll
  for (int jj = 0; jj < 8; ++jj) {
    const int k = g * 8 + jj;
    const float vr = (k < 16) ? W[k * 16 + lm]  : W0[(k - 16) * 16 + lm];
    const float vs = (k < 16) ? W1[k * 16 + lm] : W01[(k - 16) * 16 + lm];
    wfr[jj] = (short)f2bf(vr);
    wfs[jj] = (short)f2bf(vs);
  }
  const float bias = bW[lm] + b0[lm] + b1[lm] + b01[lm];

  __syncthreads();

  // ---- phase 1b: projection MFMAs; r accumulates in acc, s -> St ----
  f32x4 acc[4];
#pragma unroll
  for (int i = 0; i < 4; ++i) {
    const int grp = wmi * 16 + wq * 4 + i;       // group of 16 rows
    const int row = grp * 16 + lm;               // j_global
    bf16x8 a;
    if (g < 2)
      a = *reinterpret_cast<const bf16x8*>(&As[0][row * 16 + g * 8]);
    else
      a = *reinterpret_cast<const bf16x8*>(&As[1][row * 16 + (g - 2) * 8]);

    f32x4 cb; cb[0] = bias; cb[1] = bias; cb[2] = bias; cb[3] = bias;
    acc[i] = __builtin_amdgcn_mfma_f32_16x16x32_bf16(a, wfr, cb, 0, 0, 0);
    const f32x4 sD = __builtin_amdgcn_mfma_f32_16x16x32_bf16(a, wfs, (f32x4)0.f, 0, 0, 0);

    // s -> St: m = wmi*16+lm (e=lm), j_local = wq*64+i*16+g*4+rr
    const int m = wmi * 16 + lm;
    const int kc = wq * 2 + (i >> 1);
    const int chunkL = ((i & 1) << 1) + (g >> 1);
    const int phys = chunkL ^ ((m >> 1) & 3);
    unsigned pw[2] = {pkbf(sD[0], sD[1]), pkbf(sD[2], sD[3])};
    *reinterpret_cast<uint2*>(&St[kc][m][phys * 8 + (g & 1) * 4]) =
        *reinterpret_cast<const uint2*>(pw);
  }

  __syncthreads();   // St complete; X/Y reads done -> As free for staging

  // ---- phase 2: mode1 GEMM (mode1c loop structure) ----
  const int srow = wid * 32 + (lane >> 2);
  const int schk = (lane & 3) * 8;

#define STAGEA(buf, kc)                                                    \
  do {                                                                     \
    GLDS16(A1t + (size_t)srow * 256 + (kc) * 32 + schk,                    \
           &As[buf][(wid * 32) * 32]);                                     \
    GLDS16(A1t + (size_t)(srow + 16) * 256 + (kc) * 32 + schk,             \
           &As[buf][(wid * 32 + 16) * 32]);                                \
  } while (0)

  int aro[4];
#pragma unroll
  for (int f = 0; f < 4; ++f) {
    const int ra = wq * 64 + f * 16 + lm;
    aro[f] = ra * 32 + ((g ^ ((ra >> 1) & 3)) << 3);
  }
  const int rwB = wmi * 16 + lm;
  const int bofs = (rwB * 32) + ((g ^ ((rwB >> 1) & 3)) << 3);

  STAGEA(0, 0);
  int cur = 0;
  for (int kc = 0; kc < 8; ++kc) {
    if (kc < 7) {
      STAGEA(cur ^ 1, kc + 1);
      asm volatile("s_waitcnt vmcnt(2)" ::: "memory");
    } else {
      asm volatile("s_waitcnt vmcnt(0)" ::: "memory");
    }
    __builtin_amdgcn_s_barrier();
    __builtin_amdgcn_sched_barrier(0);

    bf16x8 af[4];
#pragma unroll
    for (int f = 0; f < 4; ++f)
      af[f] = *reinterpret_cast<const bf16x8*>(&As[cur][aro[f]]);
    const bf16x8 bfr = *reinterpret_cast<const bf16x8*>(&St[kc][0][0] + bofs);

#pragma unroll
    for (int i = 0; i < 4; ++i)
      acc[i] = __builtin_amdgcn_mfma_f32_16x16x32_bf16(af[i], bfr, acc[i], 0, 0, 0);

    __builtin_amdgcn_sched_barrier(0);
    __builtin_amdgcn_s_barrier();
    cur ^= 1;
  }
#undef STAGEA

  // ---- epilogue: out = relu(acc), single fp32 write ----
  float* os = out + (sl0 + wmi) * NCOL;
#pragma unroll
  for (int i = 0; i < 4; ++i) {
    const int qb = wq * 64 + i * 16 + g * 4;
#pragma unroll
    for (int rr = 0; rr < 4; ++rr)
      os[(size_t)(qb + rr) * EE + lm] = fmaxf(acc[i][rr], 0.f);
  }
}

// ---------------------------------------------------------------------------
extern "C" void kernel_launch(void* const* d_in, const int* in_sizes, int n_in,
                              void* d_out, int out_size, void* d_ws, size_t ws_size,
                              hipStream_t stream) {
  const float* x    = (const float*)d_in[0];
  const float* adj0 = (const float*)d_in[1];
  const float* adj1 = (const float*)d_in[2];
  const float* W    = (const float*)d_in[3];
  const float* bW   = (const float*)d_in[4];
  const float* Ws0  = (const float*)d_in[5];
  const float* bs0  = (const float*)d_in[6];
  const float* Ws1  = (const float*)d_in[7];
  const float* bs1  = (const float*)d_in[8];
  const float* Ws01 = (const float*)d_in[9];
  const float* bs01 = (const float*)d_in[10];
  float* out = (float*)d_out;

  const size_t SLICE = (size_t)NN1 * NCOL;
  const size_t AT_B  = (size_t)1024 * 1024 * 2;      // adj0^T bf16 swz
  const size_t A1T_B = (size_t)256 * 256 * 2;        // adj1^T bf16 swz
  const size_t XT_B  = (size_t)NCOL * 1024 * 2;      // per-batch, 8.4 MB
  const size_t Y0_B  = SLICE * 2;                    // per-batch bf16
  const size_t HEAD  = AT_B + A1T_B;
  const size_t PER_B = XT_B + Y0_B;

  int nb_max = (int)((ws_size > HEAD ? ws_size - HEAD : 0) / PER_B);
  if (nb_max > BB) nb_max = BB;
  if (nb_max < 1)  nb_max = 1;

  ushort* At  = (ushort*)d_ws;
  ushort* A1t = (ushort*)((char*)d_ws + AT_B);
  ushort* Xt  = (ushort*)((char*)d_ws + HEAD);
  ushort* y0  = (ushort*)((char*)d_ws + HEAD + (size_t)nb_max * XT_B);

  k_prep<<<dim3(16, 16, 1), 256, 0, stream>>>(adj0, At, 1024, 1024, 0, 0);
  k_prep<<<dim3(4, 4, 1), 256, 0, stream>>>(adj1, A1t, 256, 256, 0, 0);

  for (int c0 = 0; c0 < BB; c0 += nb_max) {
    const int nb = (BB - c0 < nb_max) ? (BB - c0) : nb_max;
    const float* xc = x   + (size_t)c0 * SLICE;
    float*       oc = out + (size_t)c0 * SLICE;

    k_prep<<<dim3(NCOL / 64, 16, nb), 256, 0, stream>>>(
        xc, Xt, NCOL, 1024, SLICE, (size_t)NCOL * 1024);

    dim3 g1(nb * 32, 8);
    k_mode0_mfma<<<g1, 256, 0, stream>>>(At, Xt, y0);

    dim3 g2(nb * NN1 / SLPB);
    k_pm<<<g2, 512, 0, stream>>>(xc, y0, A1t, W, bW, Ws0, bs0,
                                 Ws1, bs1, Ws01, bs01, oc);
  }
}